// Round 12
// baseline (411.670 us; speedup 1.0000x reference)
//
#include <hip/hip_runtime.h>
#include <hip/hip_bf16.h>
#include <math.h>

#define NN 20000
#define EE 320000
#define MM 3
#define FW 256        // NH*HID = NHO*OUT = 256
#define SAH 128
#define NB 79         // ceil(NN/256)
#define RNG 2500      // NN/8 : dst-range per XCD for the scatter

typedef __attribute__((ext_vector_type(8))) short bf16x8;
typedef __attribute__((ext_vector_type(4))) float f32x4;

static __device__ __forceinline__ float lrelu(float x){ return x > 0.f ? x : 0.2f*x; }

// fp32 -> bf16 round-to-nearest-even
static __device__ __forceinline__ unsigned short f2bf(float f) {
    unsigned u = __float_as_uint(f);
    return (unsigned short)((u + 0x7FFFu + ((u >> 16) & 1u)) >> 16);
}
static __device__ __forceinline__ float bflo(unsigned u){ return __uint_as_float(u << 16); }
static __device__ __forceinline__ float bfhi(unsigned u){ return __uint_as_float(u & 0xffff0000u); }
static __device__ __forceinline__ unsigned pk2bf(float lo, float hi) {
    return ((unsigned)f2bf(lo)) | (((unsigned)f2bf(hi)) << 16);
}

// ---------------- prep: x -> bf16; weights -> transposed bf16; zero cnt/wsum ----------------
#define XBLK 2500   // 2500*256 threads * 8 elems = 5.12M = NN*256
#define ZBLK 235    // 235*256 >= MM*NN ints for cnt zeroing
__global__ __launch_bounds__(256) void prep_kernel(const float* __restrict__ x, unsigned short* __restrict__ xb,
                                                   const float* __restrict__ W1, unsigned short* __restrict__ W1t,
                                                   const float* __restrict__ saW1, unsigned short* __restrict__ saW1t,
                                                   const float* __restrict__ W2, unsigned short* __restrict__ W2t,
                                                   const float* __restrict__ saW2, unsigned short* __restrict__ saW2t,
                                                   int* __restrict__ cnt, float* __restrict__ wsum) {
    int b = blockIdx.x, tid = threadIdx.x;
    if (b < XBLK) {
        int i = b*256 + tid;           // uint4 index, 8 elems each
        const float4* p = (const float4*)x + (size_t)i*2;
        float4 v0 = p[0], v1 = p[1];
        uint4 o;
        o.x = pk2bf(v0.x, v0.y); o.y = pk2bf(v0.z, v0.w);
        o.z = pk2bf(v1.x, v1.y); o.w = pk2bf(v1.z, v1.w);
        ((uint4*)xb)[i] = o;
        return;
    }
    int b2 = b - XBLK;
    if (b2 < 256)      { int n = b2;       W1t  [(size_t)n*256 + tid] = f2bf(W1  [(size_t)tid*256 + n]); return; }
    else if (b2 < 384) { int n = b2 - 256; saW1t[(size_t)n*256 + tid] = f2bf(saW1[(size_t)tid*SAH + n]); return; }
    else if (b2 < 640) { int n = b2 - 384; W2t  [(size_t)n*256 + tid] = f2bf(W2  [(size_t)tid*256 + n]); return; }
    else if (b2 < 768) { int n = b2 - 640; saW2t[(size_t)n*256 + tid] = f2bf(saW2[(size_t)tid*SAH + n]); return; }
    int zb = b2 - 768;
    int i = zb*256 + tid;
    if (i < MM*NN) cnt[i] = 0;
    if (zb == 0 && tid < 8) wsum[tid] = 0.f;
}

// ---------------- CSR build ----------------
// 4 edges per thread (int4 loads)
__global__ __launch_bounds__(256) void hist_kernel(const int* __restrict__ edges, int* __restrict__ cnt) {
    int idx = blockIdx.x*256 + threadIdx.x;
    if (idx >= MM*EE/4) return;
    int m = idx / (EE/4), e4 = idx - m*(EE/4);
    int4 d = ((const int4*)(edges + (size_t)(m*2+1)*EE))[e4];
    atomicAdd(&cnt[m*NN + d.x], 1);
    atomicAdd(&cnt[m*NN + d.y], 1);
    atomicAdd(&cnt[m*NN + d.z], 1);
    atomicAdd(&cnt[m*NN + d.w], 1);
}

__global__ __launch_bounds__(256) void scanA_kernel(const int* __restrict__ cnt, int* __restrict__ rowptr, int* __restrict__ bsum) {
    int m = blockIdx.y;
    int i = blockIdx.x*256 + threadIdx.x;
    int v = (i < NN) ? cnt[m*NN + i] : 0;
    int lane = threadIdx.x & 63;
    int val = v;
    #pragma unroll
    for (int o = 1; o < 64; o <<= 1) { int t = __shfl_up(val, o); if (lane >= o) val += t; }
    __shared__ int ws[4];
    int w = threadIdx.x >> 6;
    if (lane == 63) ws[w] = val;
    __syncthreads();
    #pragma unroll
    for (int j = 0; j < 3; ++j) if (j < w) val += ws[j];
    if (i < NN) rowptr[m*(NN+1) + 1 + i] = val;
    if (threadIdx.x == 255) bsum[m*NB + blockIdx.x] = val;
}

__global__ __launch_bounds__(128) void scanB_kernel(const int* __restrict__ bsum, int* __restrict__ boff) {
    __shared__ int s[128];
    int t = threadIdx.x;
    for (int m = 0; m < MM; ++m) {
        int v = (t < NB) ? bsum[m*NB + t] : 0;
        s[t] = v; __syncthreads();
        for (int o = 1; o < 128; o <<= 1) {
            int x = (t >= o) ? s[t - o] : 0;
            __syncthreads();
            s[t] += x;
            __syncthreads();
        }
        if (t < NB) boff[m*NB + t] = s[t] - v;   // exclusive
        __syncthreads();
    }
}

__global__ __launch_bounds__(256) void scanC_kernel(const int* __restrict__ cnt, int* __restrict__ rowptr,
                                                    const int* __restrict__ boff, int* __restrict__ cursor) {
    int m = blockIdx.y;
    int i = blockIdx.x*256 + threadIdx.x;
    if (i >= NN) return;
    int incl = rowptr[m*(NN+1) + 1 + i] + boff[m*NB + blockIdx.x];
    rowptr[m*(NN+1) + 1 + i] = incl;
    cursor[m*NN + i] = incl - cnt[m*NN + i];
    if (i == 0 && blockIdx.x == 0) rowptr[m*(NN+1)] = 0;
}

// dst-range-partitioned scatter (XCD-local csr segments); packed (src,dst) 8B
__global__ __launch_bounds__(256) void scatter_kernel(const int* __restrict__ edges, int* __restrict__ cursor,
                                                      uint2* __restrict__ csr) {
    int m = blockIdx.y;
    int r = blockIdx.x & 7;
    int chunk = blockIdx.x >> 3;
    int e4 = chunk*256 + threadIdx.x;
    if (e4 >= EE/4) return;
    int lo = r * RNG, hi = lo + RNG;
    int4 s = ((const int4*)(edges + (size_t)(m*2  )*EE))[e4];
    int4 d = ((const int4*)(edges + (size_t)(m*2+1)*EE))[e4];
    if (d.x >= lo && d.x < hi) { int p = atomicAdd(&cursor[m*NN + d.x], 1); csr[(size_t)m*EE + p] = make_uint2((unsigned)s.x, (unsigned)d.x); }
    if (d.y >= lo && d.y < hi) { int p = atomicAdd(&cursor[m*NN + d.y], 1); csr[(size_t)m*EE + p] = make_uint2((unsigned)s.y, (unsigned)d.y); }
    if (d.z >= lo && d.z < hi) { int p = atomicAdd(&cursor[m*NN + d.z], 1); csr[(size_t)m*EE + p] = make_uint2((unsigned)s.z, (unsigned)d.z); }
    if (d.w >= lo && d.w < hi) { int p = atomicAdd(&cursor[m*NN + d.w], 1); csr[(size_t)m*EE + p] = make_uint2((unsigned)s.w, (unsigned)d.w); }
}

// ---------------- MFMA GEMM + el/er epilogue ----------------
template<int H>
__global__ __launch_bounds__(256) void gemm_mfma_kernel(const unsigned short* __restrict__ A,
                                                        const unsigned short* __restrict__ Bt,
                                                        const float* __restrict__ attl, const float* __restrict__ attr,
                                                        unsigned short* __restrict__ C,
                                                        float* __restrict__ el, float* __restrict__ er) {
    int tid = threadIdx.x;
    int w = tid >> 6, lane = tid & 63;
    int rowgrp = w & 1, half = w >> 1;
    int r0 = blockIdx.x*32 + rowgrp*16;
    int colbase = half * 128;
    int lrow = lane & 15, lk = lane >> 4;

    bf16x8 a[8];
    const unsigned short* ap = A + (size_t)(r0 + lrow)*256 + lk*8;
    #pragma unroll
    for (int k = 0; k < 8; ++k) a[k] = *(const bf16x8*)(ap + k*32);

    float pelv[2][4] = {{0.f,0.f,0.f,0.f},{0.f,0.f,0.f,0.f}};
    float perv[2][4] = {{0.f,0.f,0.f,0.f},{0.f,0.f,0.f,0.f}};

    #pragma unroll
    for (int n = 0; n < 8; ++n) {
        int col0 = colbase + n*16;
        const unsigned short* bp = Bt + (size_t)(col0 + lrow)*256 + lk*8;
        f32x4 acc = {0.f, 0.f, 0.f, 0.f};
        #pragma unroll
        for (int k = 0; k < 8; ++k) {
            bf16x8 bfr = *(const bf16x8*)(bp + k*32);
            acc = __builtin_amdgcn_mfma_f32_16x16x32_bf16(a[k], bfr, acc, 0, 0, 0);
        }
        int col = col0 + lrow;
        float al = attl[col], ar = attr[col];
        int hl = (H == 4) ? (n >> 2) : 0;
        #pragma unroll
        for (int r = 0; r < 4; ++r) {
            float cv = acc[r];
            pelv[hl][r] += cv * al;
            perv[hl][r] += cv * ar;
            C[(size_t)(r0 + lk*4 + r)*256 + col] = f2bf(cv);
        }
    }

    int nhl = (H == 4) ? 2 : 1;
    #pragma unroll
    for (int hl = 0; hl < 2; ++hl) {
        if (hl >= nhl) break;
        #pragma unroll
        for (int r = 0; r < 4; ++r) {
            float pe = pelv[hl][r], pr = perv[hl][r];
            #pragma unroll
            for (int o = 1; o < 16; o <<= 1) { pe += __shfl_xor(pe, o); pr += __shfl_xor(pr, o); }
            pelv[hl][r] = pe; perv[hl][r] = pr;
        }
    }

    if (H == 4) {
        if (lrow == 0) {
            int row = r0 + lk*4;
            #pragma unroll
            for (int hl = 0; hl < 2; ++hl) {
                int head = half*2 + hl;
                #pragma unroll
                for (int r = 0; r < 4; ++r) {
                    el[(size_t)(row + r)*4 + head] = pelv[hl][r];
                    er[(size_t)(row + r)*4 + head] = perv[hl][r];
                }
            }
        }
    } else {
        __shared__ float elds[2][32], erds[2][32];
        if (lrow == 0) {
            int rib = rowgrp*16 + lk*4;
            #pragma unroll
            for (int r = 0; r < 4; ++r) {
                elds[half][rib + r] = pelv[0][r];
                erds[half][rib + r] = perv[0][r];
            }
        }
        __syncthreads();
        if (tid < 32) {
            el[blockIdx.x*32 + tid] = elds[0][tid] + elds[1][tid];
            er[blockIdx.x*32 + tid] = erds[0][tid] + erds[1][tid];
        }
    }
}

// ---------------- edge coefficients ee = exp(leakyrelu(el[src]+er[dst])) ----------------
// 2 edges per thread; csr streamed nontemporal via ull view
template<int H>
__global__ __launch_bounds__(256) void edge_ee_kernel(const unsigned long long* __restrict__ csr_ull,
                                                      const float* __restrict__ el, const float* __restrict__ er,
                                                      float* __restrict__ ee) {
    int idx = blockIdx.x*256 + threadIdx.x;
    if (idx >= MM*EE/2) return;
    unsigned long long p0 = __builtin_nontemporal_load(csr_ull + (size_t)idx*2);
    unsigned long long p1 = __builtin_nontemporal_load(csr_ull + (size_t)idx*2 + 1);
    unsigned s0 = (unsigned)p0, d0 = (unsigned)(p0 >> 32);
    unsigned s1 = (unsigned)p1, d1 = (unsigned)(p1 >> 32);
    if (H == 4) {
        float4 l0 = *(const float4*)&el[s0*4];
        float4 r0 = *(const float4*)&er[d0*4];
        float4 l1 = *(const float4*)&el[s1*4];
        float4 r1 = *(const float4*)&er[d1*4];
        float4 o0, o1;
        o0.x = expf(lrelu(l0.x + r0.x)); o0.y = expf(lrelu(l0.y + r0.y));
        o0.z = expf(lrelu(l0.z + r0.z)); o0.w = expf(lrelu(l0.w + r0.w));
        o1.x = expf(lrelu(l1.x + r1.x)); o1.y = expf(lrelu(l1.y + r1.y));
        o1.z = expf(lrelu(l1.z + r1.z)); o1.w = expf(lrelu(l1.w + r1.w));
        *(float4*)&ee[(size_t)idx*8]     = o0;
        *(float4*)&ee[(size_t)idx*8 + 4] = o1;
    } else {
        float2 o;
        o.x = expf(lrelu(el[s0] + er[d0]));
        o.y = expf(lrelu(el[s1] + er[d1]));
        *(float2*)&ee[(size_t)idx*2] = o;
    }
}

// ---------------- per-dst aggregation ----------------
// One wave per (node, metapath); block = 4 waves = 4 consecutive nodes.
// 2 edge-slots of 32 lanes; each slot runs 2 edges per iteration with both
// 512B row-gathers issued back-to-back (4 outstanding per wave). csr/ee are
// single-use streams -> nontemporal loads keep feat resident in L2.
template<int H, bool RELU>
__global__ __launch_bounds__(256) void agg_kernel(const unsigned short* __restrict__ feat,
                                                  const float* __restrict__ ee,
                                                  const int* __restrict__ rowptr,
                                                  const unsigned* __restrict__ csr_u,   // uint view; src at index 2*e
                                                  unsigned short* __restrict__ z) {
    int m = blockIdx.y;
    int tid = threadIdx.x;
    int lane = tid & 63, wv = tid >> 6;
    int n = blockIdx.x * 4 + wv;
    int eslot = lane >> 5, flane = lane & 31;
    int h = (H == 4) ? (flane >> 3) : 0;
    int beg = rowptr[m*(NN+1) + n], end = rowptr[m*(NN+1) + n + 1];
    const size_t eb = (size_t)m*EE;

    float a[8] = {};
    float den = 0.f;

    // slot's edges: beg+eslot, +2, +4, ... ; process 2 per iteration
    int e = beg + eslot;
    unsigned sA = 0, sB = 0;
    float wA = 0.f, wB = 0.f;
    if (e     < end) { sA = __builtin_nontemporal_load(csr_u + (eb+e  )*2); wA = (H==4)? __builtin_nontemporal_load(&ee[(eb+e  )*4+h]) : __builtin_nontemporal_load(&ee[eb+e  ]); }
    if (e + 2 < end) { sB = __builtin_nontemporal_load(csr_u + (eb+e+2)*2); wB = (H==4)? __builtin_nontemporal_load(&ee[(eb+e+2)*4+h]) : __builtin_nontemporal_load(&ee[eb+e+2]); }

    while (e < end) {
        uint4 v0 = *(const uint4*)(feat + (size_t)sA*256 + flane*8);
        bool h1 = (e + 2 < end);
        uint4 v1 = make_uint4(0,0,0,0);
        if (h1) v1 = *(const uint4*)(feat + (size_t)sB*256 + flane*8);
        float w0 = wA, w1 = h1 ? wB : 0.f;
        if (e + 4 < end) { sA = __builtin_nontemporal_load(csr_u + (eb+e+4)*2); wA = (H==4)? __builtin_nontemporal_load(&ee[(eb+e+4)*4+h]) : __builtin_nontemporal_load(&ee[eb+e+4]); }
        if (e + 6 < end) { sB = __builtin_nontemporal_load(csr_u + (eb+e+6)*2); wB = (H==4)? __builtin_nontemporal_load(&ee[(eb+e+6)*4+h]) : __builtin_nontemporal_load(&ee[eb+e+6]); }
        den += w0 + w1;
        a[0] += w0*bflo(v0.x) + w1*bflo(v1.x);
        a[1] += w0*bfhi(v0.x) + w1*bfhi(v1.x);
        a[2] += w0*bflo(v0.y) + w1*bflo(v1.y);
        a[3] += w0*bfhi(v0.y) + w1*bfhi(v1.y);
        a[4] += w0*bflo(v0.z) + w1*bflo(v1.z);
        a[5] += w0*bfhi(v0.z) + w1*bfhi(v1.z);
        a[6] += w0*bflo(v0.w) + w1*bflo(v1.w);
        a[7] += w0*bfhi(v0.w) + w1*bfhi(v1.w);
        e += 4;
    }

    // combine the two edge-slots (lane ^ 32 holds the other slot's partial)
    #pragma unroll
    for (int j = 0; j < 8; ++j) a[j] += __shfl_xor(a[j], 32);
    den += __shfl_xor(den, 32);

    if (eslot == 0) {
        float inv = 1.f / (den + 1e-9f);
        #pragma unroll
        for (int j = 0; j < 8; ++j) {
            a[j] *= inv;
            if (RELU) a[j] = fmaxf(a[j], 0.f);
        }
        uint4 pk;
        pk.x = pk2bf(a[0], a[1]);
        pk.y = pk2bf(a[2], a[3]);
        pk.z = pk2bf(a[4], a[5]);
        pk.w = pk2bf(a[6], a[7]);
        *(uint4*)&z[((size_t)n*MM + m)*256 + flane*8] = pk;
    }
}

// ---------------- semantic attention (MFMA): wsum[m] += sum_n tanh(z@W+b)·v ----------------
__global__ __launch_bounds__(256) void semw_mfma_kernel(const unsigned short* __restrict__ Z,
                                                        const unsigned short* __restrict__ Wt,
                                                        const float* __restrict__ bias, const float* __restrict__ v,
                                                        float* __restrict__ wsum) {
    int tid = threadIdx.x;
    int w = tid >> 6, lane = tid & 63;
    int r0 = blockIdx.x*64 + w*16;
    int lrow = lane & 15, lk = lane >> 4;

    int arow = r0 + lrow;
    if (arow >= NN*MM) arow = NN*MM - 1;   // clamp; masked in epilogue
    bf16x8 a[8];
    const unsigned short* ap = Z + (size_t)arow*256 + lk*8;
    #pragma unroll
    for (int k = 0; k < 8; ++k) a[k] = *(const bf16x8*)(ap + k*32);

    float p[4] = {0.f, 0.f, 0.f, 0.f};
    #pragma unroll
    for (int n = 0; n < 8; ++n) {
        int col = n*16 + lrow;
        const unsigned short* bp = Wt + (size_t)col*256 + lk*8;
        f32x4 acc = {0.f, 0.f, 0.f, 0.f};
        #pragma unroll
        for (int k = 0; k < 8; ++k) {
            bf16x8 bfr = *(const bf16x8*)(bp + k*32);
            acc = __builtin_amdgcn_mfma_f32_16x16x32_bf16(a[k], bfr, acc, 0, 0, 0);
        }
        float bb = bias[col], vv = v[col];
        #pragma unroll
        for (int r = 0; r < 4; ++r)
            p[r] += tanhf(acc[r] + bb) * vv;
    }

    #pragma unroll
    for (int r = 0; r < 4; ++r) {
        #pragma unroll
        for (int o = 1; o < 16; o <<= 1) p[r] += __shfl_xor(p[r], o);
    }

    __shared__ float loc[3];
    if (tid < 3) loc[tid] = 0.f;
    __syncthreads();
    if (lrow == 0) {
        #pragma unroll
        for (int r = 0; r < 4; ++r) {
            int row = r0 + lk*4 + r;
            if (row < NN*MM) atomicAdd(&loc[row % MM], p[r]);
        }
    }
    __syncthreads();
    if (tid < 3) atomicAdd(&wsum[tid], loc[tid]);
}

// layer-1 combine: z (bf16) -> h (bf16); beta computed inline from wsum
__global__ __launch_bounds__(128) void combine_bf16_kernel(const unsigned short* __restrict__ z, const float* __restrict__ wsum,
                                                           unsigned short* __restrict__ outb) {
    __shared__ float bs[3];
    int n = blockIdx.x, t = threadIdx.x;
    if (t == 0) {
        float w0 = wsum[0] / (float)NN, w1 = wsum[1] / (float)NN, w2 = wsum[2] / (float)NN;
        float mx = fmaxf(w0, fmaxf(w1, w2));
        float e0 = expf(w0 - mx), e1 = expf(w1 - mx), e2 = expf(w2 - mx);
        float s = e0 + e1 + e2;
        bs[0] = e0 / s; bs[1] = e1 / s; bs[2] = e2 / s;
    }
    __syncthreads();
    float b0 = bs[0], b1 = bs[1], b2 = bs[2];
    size_t base = (size_t)n*MM*256 + t*2;
    unsigned z0 = *(const unsigned*)&z[base];
    unsigned z1 = *(const unsigned*)&z[base + 256];
    unsigned z2 = *(const unsigned*)&z[base + 512];
    float ox = b0*bflo(z0) + b1*bflo(z1) + b2*bflo(z2);
    float oy = b0*bfhi(z0) + b1*bfhi(z1) + b2*bfhi(z2);
    *(unsigned*)&outb[(size_t)n*256 + t*2] = pk2bf(ox, oy);
}

// layer-2 combine: z (bf16) -> out (fp32); also writes att_mp
__global__ __launch_bounds__(128) void combine_kernel(const unsigned short* __restrict__ z, const float* __restrict__ wsum,
                                                      float* __restrict__ out, float* __restrict__ att_out) {
    __shared__ float bs[3];
    int n = blockIdx.x, t = threadIdx.x;
    if (t == 0) {
        float w0 = wsum[0] / (float)NN, w1 = wsum[1] / (float)NN, w2 = wsum[2] / (float)NN;
        float mx = fmaxf(w0, fmaxf(w1, w2));
        float e0 = expf(w0 - mx), e1 = expf(w1 - mx), e2 = expf(w2 - mx);
        float s = e0 + e1 + e2;
        bs[0] = e0 / s; bs[1] = e1 / s; bs[2] = e2 / s;
        if (n == 0) { att_out[0] = bs[0]; att_out[1] = bs[1]; att_out[2] = bs[2]; }
    }
    __syncthreads();
    float b0 = bs[0], b1 = bs[1], b2 = bs[2];
    size_t base = (size_t)n*MM*256 + t*2;
    unsigned z0 = *(const unsigned*)&z[base];
    unsigned z1 = *(const unsigned*)&z[base + 256];
    unsigned z2 = *(const unsigned*)&z[base + 512];
    float2 o;
    o.x = b0*bflo(z0) + b1*bflo(z1) + b2*bflo(z2);
    o.y = b0*bfhi(z0) + b1*bfhi(z1) + b2*bfhi(z2);
    *(float2*)&out[(size_t)n*256 + t*2] = o;
}

extern "C" void kernel_launch(void* const* d_in, const int* in_sizes, int n_in,
                              void* d_out, int out_size, void* d_ws, size_t ws_size,
                              hipStream_t stream) {
    const float* x    = (const float*)d_in[0];
    const int*   edges= (const int*)  d_in[1];
    const float* W1   = (const float*)d_in[2];
    const float* al1  = (const float*)d_in[3];
    const float* ar1  = (const float*)d_in[4];
    const float* saW1 = (const float*)d_in[5];
    const float* sab1 = (const float*)d_in[6];
    const float* sav1 = (const float*)d_in[7];
    const float* W2   = (const float*)d_in[8];
    const float* al2  = (const float*)d_in[9];
    const float* ar2  = (const float*)d_in[10];
    const float* saW2 = (const float*)d_in[11];
    const float* sab2 = (const float*)d_in[12];
    const float* sav2 = (const float*)d_in[13];
    float* out = (float*)d_out;

    char* ws = (char*)d_ws;
    size_t off = 0;
    auto alloc = [&](size_t bytes) { void* p = ws + off; off += (bytes + 255) & ~(size_t)255; return p; };
    unsigned short* feat  = (unsigned short*)alloc((size_t)NN*256*2);      // bf16
    unsigned short* z     = (unsigned short*)alloc((size_t)NN*MM*256*2);   // bf16
    unsigned short* xb    = (unsigned short*)alloc((size_t)NN*256*2);      // bf16 x  (reused as hb)
    unsigned short* W1t   = (unsigned short*)alloc(256*256*2);
    unsigned short* saW1t = (unsigned short*)alloc(SAH*256*2);
    unsigned short* W2t   = (unsigned short*)alloc(256*256*2);
    unsigned short* saW2t = (unsigned short*)alloc(SAH*256*2);
    float* ee     = (float*)alloc((size_t)MM*EE*4*4);
    float* el     = (float*)alloc(NN*4*4);
    float* er     = (float*)alloc(NN*4*4);
    float* wsum   = (float*)alloc(256);        // [0..3]=layer1, [4..7]=layer2
    int*   cnt    = (int*)alloc(MM*NN*4);
    int*   cursor = (int*)alloc(MM*NN*4);
    int*   rowptr = (int*)alloc(MM*(NN+1)*4);
    uint2* csr    = (uint2*)alloc((size_t)MM*EE*8);
    int*   bsum   = (int*)alloc(MM*NB*4);
    int*   boff   = (int*)alloc(MM*NB*4);
    unsigned short* hb = xb;   // layer-1 output (bf16), reuses xb space

    int egrid2 = (MM*EE/2 + 255)/256;
    int egrid4 = (MM*EE/4 + 255)/256;
    int chunks = (EE/4 + 255)/256;            // 313
    dim3 sg(NB, MM);

    // prep: x->bf16, weights -> transposed bf16, zero cnt/wsum
    prep_kernel<<<XBLK + 768 + ZBLK, 256, 0, stream>>>(x, xb, W1, W1t, saW1, saW1t, W2, W2t, saW2, saW2t, cnt, wsum);

    // CSR build (shared by both layers)
    hist_kernel<<<egrid4, 256, 0, stream>>>(edges, cnt);
    scanA_kernel<<<sg, 256, 0, stream>>>(cnt, rowptr, bsum);
    scanB_kernel<<<1, 128, 0, stream>>>(bsum, boff);
    scanC_kernel<<<sg, 256, 0, stream>>>(cnt, rowptr, boff, cursor);
    scatter_kernel<<<dim3(chunks*8, MM), 256, 0, stream>>>(edges, cursor, csr);

    // ---- layer 1 ----
    gemm_mfma_kernel<4><<<NN/32, 256, 0, stream>>>(xb, W1t, al1, ar1, feat, el, er);
    edge_ee_kernel<4><<<egrid2, 256, 0, stream>>>((const unsigned long long*)csr, el, er, ee);
    agg_kernel<4, true><<<dim3(NN/4, MM), 256, 0, stream>>>(feat, ee, rowptr, (const unsigned*)csr, z);
    semw_mfma_kernel<<<(NN*MM + 63)/64, 256, 0, stream>>>(z, saW1t, sab1, sav1, wsum);
    combine_bf16_kernel<<<NN, 128, 0, stream>>>(z, wsum, hb);

    // ---- layer 2 ----
    gemm_mfma_kernel<1><<<NN/32, 256, 0, stream>>>(hb, W2t, al2, ar2, feat, el, er);
    edge_ee_kernel<1><<<egrid2, 256, 0, stream>>>((const unsigned long long*)csr, el, er, ee);
    agg_kernel<1, false><<<dim3(NN/4, MM), 256, 0, stream>>>(feat, ee, rowptr, (const unsigned*)csr, z);
    semw_mfma_kernel<<<(NN*MM + 63)/64, 256, 0, stream>>>(z, saW2t, sab2, sav2, wsum + 4);
    combine_kernel<<<NN, 128, 0, stream>>>(z, wsum + 4, out, out + (size_t)NN*256);
}

// Round 13
// 389.420 us; speedup vs baseline: 1.0571x; 1.0571x over previous
//
#include <hip/hip_runtime.h>
#include <hip/hip_bf16.h>
#include <math.h>

#define NN 20000
#define EE 320000
#define MM 3
#define FW 256        // NH*HID = NHO*OUT = 256
#define SAH 128
#define NB 79         // ceil(NN/256)
#define RNG 2500      // NN/8 : dst-range per XCD for the scatter

typedef __attribute__((ext_vector_type(8))) short bf16x8;
typedef __attribute__((ext_vector_type(4))) float f32x4;

static __device__ __forceinline__ float lrelu(float x){ return x > 0.f ? x : 0.2f*x; }

// fp32 -> bf16 round-to-nearest-even
static __device__ __forceinline__ unsigned short f2bf(float f) {
    unsigned u = __float_as_uint(f);
    return (unsigned short)((u + 0x7FFFu + ((u >> 16) & 1u)) >> 16);
}
static __device__ __forceinline__ float bf2f(unsigned short b) {
    return __uint_as_float(((unsigned)b) << 16);
}
static __device__ __forceinline__ float bflo(unsigned u){ return __uint_as_float(u << 16); }
static __device__ __forceinline__ float bfhi(unsigned u){ return __uint_as_float(u & 0xffff0000u); }
static __device__ __forceinline__ unsigned pk2bf(float lo, float hi) {
    return ((unsigned)f2bf(lo)) | (((unsigned)f2bf(hi)) << 16);
}

// ---------------- prep: x -> bf16; weights -> transposed bf16; zero cnt/wsum ----------------
#define XBLK 2500   // 2500*256 threads * 8 elems = 5.12M = NN*256
#define ZBLK 235    // 235*256 >= MM*NN ints for cnt zeroing
__global__ __launch_bounds__(256) void prep_kernel(const float* __restrict__ x, unsigned short* __restrict__ xb,
                                                   const float* __restrict__ W1, unsigned short* __restrict__ W1t,
                                                   const float* __restrict__ saW1, unsigned short* __restrict__ saW1t,
                                                   const float* __restrict__ W2, unsigned short* __restrict__ W2t,
                                                   const float* __restrict__ saW2, unsigned short* __restrict__ saW2t,
                                                   int* __restrict__ cnt, float* __restrict__ wsum) {
    int b = blockIdx.x, tid = threadIdx.x;
    if (b < XBLK) {
        int i = b*256 + tid;           // uint4 index, 8 elems each
        const float4* p = (const float4*)x + (size_t)i*2;
        float4 v0 = p[0], v1 = p[1];
        uint4 o;
        o.x = pk2bf(v0.x, v0.y); o.y = pk2bf(v0.z, v0.w);
        o.z = pk2bf(v1.x, v1.y); o.w = pk2bf(v1.z, v1.w);
        ((uint4*)xb)[i] = o;
        return;
    }
    int b2 = b - XBLK;
    if (b2 < 256)      { int n = b2;       W1t  [(size_t)n*256 + tid] = f2bf(W1  [(size_t)tid*256 + n]); return; }
    else if (b2 < 384) { int n = b2 - 256; saW1t[(size_t)n*256 + tid] = f2bf(saW1[(size_t)tid*SAH + n]); return; }
    else if (b2 < 640) { int n = b2 - 384; W2t  [(size_t)n*256 + tid] = f2bf(W2  [(size_t)tid*256 + n]); return; }
    else if (b2 < 768) { int n = b2 - 640; saW2t[(size_t)n*256 + tid] = f2bf(saW2[(size_t)tid*SAH + n]); return; }
    int zb = b2 - 768;
    int i = zb*256 + tid;
    if (i < MM*NN) cnt[i] = 0;
    if (zb == 0 && tid < 8) wsum[tid] = 0.f;
}

// ---------------- CSR build ----------------
// 4 edges per thread (int4 loads)
__global__ __launch_bounds__(256) void hist_kernel(const int* __restrict__ edges, int* __restrict__ cnt) {
    int idx = blockIdx.x*256 + threadIdx.x;
    if (idx >= MM*EE/4) return;
    int m = idx / (EE/4), e4 = idx - m*(EE/4);
    int4 d = ((const int4*)(edges + (size_t)(m*2+1)*EE))[e4];
    atomicAdd(&cnt[m*NN + d.x], 1);
    atomicAdd(&cnt[m*NN + d.y], 1);
    atomicAdd(&cnt[m*NN + d.z], 1);
    atomicAdd(&cnt[m*NN + d.w], 1);
}

__global__ __launch_bounds__(256) void scanA_kernel(const int* __restrict__ cnt, int* __restrict__ rowptr, int* __restrict__ bsum) {
    int m = blockIdx.y;
    int i = blockIdx.x*256 + threadIdx.x;
    int v = (i < NN) ? cnt[m*NN + i] : 0;
    int lane = threadIdx.x & 63;
    int val = v;
    #pragma unroll
    for (int o = 1; o < 64; o <<= 1) { int t = __shfl_up(val, o); if (lane >= o) val += t; }
    __shared__ int ws[4];
    int w = threadIdx.x >> 6;
    if (lane == 63) ws[w] = val;
    __syncthreads();
    #pragma unroll
    for (int j = 0; j < 3; ++j) if (j < w) val += ws[j];
    if (i < NN) rowptr[m*(NN+1) + 1 + i] = val;
    if (threadIdx.x == 255) bsum[m*NB + blockIdx.x] = val;
}

__global__ __launch_bounds__(128) void scanB_kernel(const int* __restrict__ bsum, int* __restrict__ boff) {
    __shared__ int s[128];
    int t = threadIdx.x;
    for (int m = 0; m < MM; ++m) {
        int v = (t < NB) ? bsum[m*NB + t] : 0;
        s[t] = v; __syncthreads();
        for (int o = 1; o < 128; o <<= 1) {
            int x = (t >= o) ? s[t - o] : 0;
            __syncthreads();
            s[t] += x;
            __syncthreads();
        }
        if (t < NB) boff[m*NB + t] = s[t] - v;   // exclusive
        __syncthreads();
    }
}

__global__ __launch_bounds__(256) void scanC_kernel(const int* __restrict__ cnt, int* __restrict__ rowptr,
                                                    const int* __restrict__ boff, int* __restrict__ cursor) {
    int m = blockIdx.y;
    int i = blockIdx.x*256 + threadIdx.x;
    if (i >= NN) return;
    int incl = rowptr[m*(NN+1) + 1 + i] + boff[m*NB + blockIdx.x];
    rowptr[m*(NN+1) + 1 + i] = incl;
    cursor[m*NN + i] = incl - cnt[m*NN + i];
    if (i == 0 && blockIdx.x == 0) rowptr[m*(NN+1)] = 0;
}

// dst-range-partitioned scatter (XCD-local csr segments); packed (src,dst) 8B
__global__ __launch_bounds__(256) void scatter_kernel(const int* __restrict__ edges, int* __restrict__ cursor,
                                                      uint2* __restrict__ csr) {
    int m = blockIdx.y;
    int r = blockIdx.x & 7;
    int chunk = blockIdx.x >> 3;
    int e4 = chunk*256 + threadIdx.x;
    if (e4 >= EE/4) return;
    int lo = r * RNG, hi = lo + RNG;
    int4 s = ((const int4*)(edges + (size_t)(m*2  )*EE))[e4];
    int4 d = ((const int4*)(edges + (size_t)(m*2+1)*EE))[e4];
    if (d.x >= lo && d.x < hi) { int p = atomicAdd(&cursor[m*NN + d.x], 1); csr[(size_t)m*EE + p] = make_uint2((unsigned)s.x, (unsigned)d.x); }
    if (d.y >= lo && d.y < hi) { int p = atomicAdd(&cursor[m*NN + d.y], 1); csr[(size_t)m*EE + p] = make_uint2((unsigned)s.y, (unsigned)d.y); }
    if (d.z >= lo && d.z < hi) { int p = atomicAdd(&cursor[m*NN + d.z], 1); csr[(size_t)m*EE + p] = make_uint2((unsigned)s.z, (unsigned)d.z); }
    if (d.w >= lo && d.w < hi) { int p = atomicAdd(&cursor[m*NN + d.w], 1); csr[(size_t)m*EE + p] = make_uint2((unsigned)s.w, (unsigned)d.w); }
}

// ---------------- MFMA GEMM + el/er epilogue ----------------
template<int H>
__global__ __launch_bounds__(256) void gemm_mfma_kernel(const unsigned short* __restrict__ A,
                                                        const unsigned short* __restrict__ Bt,
                                                        const float* __restrict__ attl, const float* __restrict__ attr,
                                                        unsigned short* __restrict__ C,
                                                        float* __restrict__ el, float* __restrict__ er) {
    int tid = threadIdx.x;
    int w = tid >> 6, lane = tid & 63;
    int rowgrp = w & 1, half = w >> 1;
    int r0 = blockIdx.x*32 + rowgrp*16;
    int colbase = half * 128;
    int lrow = lane & 15, lk = lane >> 4;

    bf16x8 a[8];
    const unsigned short* ap = A + (size_t)(r0 + lrow)*256 + lk*8;
    #pragma unroll
    for (int k = 0; k < 8; ++k) a[k] = *(const bf16x8*)(ap + k*32);

    float pelv[2][4] = {{0.f,0.f,0.f,0.f},{0.f,0.f,0.f,0.f}};
    float perv[2][4] = {{0.f,0.f,0.f,0.f},{0.f,0.f,0.f,0.f}};

    #pragma unroll
    for (int n = 0; n < 8; ++n) {
        int col0 = colbase + n*16;
        const unsigned short* bp = Bt + (size_t)(col0 + lrow)*256 + lk*8;
        f32x4 acc = {0.f, 0.f, 0.f, 0.f};
        #pragma unroll
        for (int k = 0; k < 8; ++k) {
            bf16x8 bfr = *(const bf16x8*)(bp + k*32);
            acc = __builtin_amdgcn_mfma_f32_16x16x32_bf16(a[k], bfr, acc, 0, 0, 0);
        }
        int col = col0 + lrow;
        float al = attl[col], ar = attr[col];
        int hl = (H == 4) ? (n >> 2) : 0;
        #pragma unroll
        for (int r = 0; r < 4; ++r) {
            float cv = acc[r];
            pelv[hl][r] += cv * al;
            perv[hl][r] += cv * ar;
            C[(size_t)(r0 + lk*4 + r)*256 + col] = f2bf(cv);
        }
    }

    int nhl = (H == 4) ? 2 : 1;
    #pragma unroll
    for (int hl = 0; hl < 2; ++hl) {
        if (hl >= nhl) break;
        #pragma unroll
        for (int r = 0; r < 4; ++r) {
            float pe = pelv[hl][r], pr = perv[hl][r];
            #pragma unroll
            for (int o = 1; o < 16; o <<= 1) { pe += __shfl_xor(pe, o); pr += __shfl_xor(pr, o); }
            pelv[hl][r] = pe; perv[hl][r] = pr;
        }
    }

    if (H == 4) {
        if (lrow == 0) {
            int row = r0 + lk*4;
            #pragma unroll
            for (int hl = 0; hl < 2; ++hl) {
                int head = half*2 + hl;
                #pragma unroll
                for (int r = 0; r < 4; ++r) {
                    el[(size_t)(row + r)*4 + head] = pelv[hl][r];
                    er[(size_t)(row + r)*4 + head] = perv[hl][r];
                }
            }
        }
    } else {
        __shared__ float elds[2][32], erds[2][32];
        if (lrow == 0) {
            int rib = rowgrp*16 + lk*4;
            #pragma unroll
            for (int r = 0; r < 4; ++r) {
                elds[half][rib + r] = pelv[0][r];
                erds[half][rib + r] = perv[0][r];
            }
        }
        __syncthreads();
        if (tid < 32) {
            el[blockIdx.x*32 + tid] = elds[0][tid] + elds[1][tid];
            er[blockIdx.x*32 + tid] = erds[0][tid] + erds[1][tid];
        }
    }
}

// ---------------- edge coefficients ee = exp(leakyrelu(el[src]+er[dst])), stored bf16 ----------------
// 2 edges per thread (one 16B csr read via ull pair)
template<int H>
__global__ __launch_bounds__(256) void edge_ee_kernel(const unsigned long long* __restrict__ csr_ull,
                                                      const float* __restrict__ el, const float* __restrict__ er,
                                                      unsigned short* __restrict__ ee16) {
    int idx = blockIdx.x*256 + threadIdx.x;
    if (idx >= MM*EE/2) return;
    unsigned long long p0 = csr_ull[(size_t)idx*2];
    unsigned long long p1 = csr_ull[(size_t)idx*2 + 1];
    unsigned s0 = (unsigned)p0, d0 = (unsigned)(p0 >> 32);
    unsigned s1 = (unsigned)p1, d1 = (unsigned)(p1 >> 32);
    if (H == 4) {
        float4 l0 = *(const float4*)&el[s0*4];
        float4 r0 = *(const float4*)&er[d0*4];
        float4 l1 = *(const float4*)&el[s1*4];
        float4 r1 = *(const float4*)&er[d1*4];
        uint4 o;
        o.x = pk2bf(expf(lrelu(l0.x + r0.x)), expf(lrelu(l0.y + r0.y)));
        o.y = pk2bf(expf(lrelu(l0.z + r0.z)), expf(lrelu(l0.w + r0.w)));
        o.z = pk2bf(expf(lrelu(l1.x + r1.x)), expf(lrelu(l1.y + r1.y)));
        o.w = pk2bf(expf(lrelu(l1.z + r1.z)), expf(lrelu(l1.w + r1.w)));
        *(uint4*)&ee16[(size_t)idx*8] = o;
    } else {
        unsigned o = pk2bf(expf(lrelu(el[s0] + er[d0])), expf(lrelu(el[s1] + er[d1])));
        *(unsigned*)&ee16[(size_t)idx*2] = o;
    }
}

// ---------------- per-dst aggregation ----------------
// One wave per (node, metapath); block = 4 waves = 4 consecutive nodes.
// 2 edge-slots of 32 lanes; each slot runs 2 edges per iteration with both
// 512B row-gathers issued back-to-back (4 outstanding per wave). ee is bf16.
template<int H, bool RELU>
__global__ __launch_bounds__(256) void agg_kernel(const unsigned short* __restrict__ feat,
                                                  const unsigned short* __restrict__ ee16,
                                                  const int* __restrict__ rowptr,
                                                  const unsigned* __restrict__ csr_u,   // uint view; src at index 2*e
                                                  unsigned short* __restrict__ z) {
    int m = blockIdx.y;
    int tid = threadIdx.x;
    int lane = tid & 63, wv = tid >> 6;
    int n = blockIdx.x * 4 + wv;
    int eslot = lane >> 5, flane = lane & 31;
    int h = (H == 4) ? (flane >> 3) : 0;
    int beg = rowptr[m*(NN+1) + n], end = rowptr[m*(NN+1) + n + 1];
    const size_t eb = (size_t)m*EE;

    float a[8] = {};
    float den = 0.f;

    // slot's edges: beg+eslot, +2, +4, ... ; process 2 per iteration
    int e = beg + eslot;
    unsigned sA = 0, sB = 0;
    float wA = 0.f, wB = 0.f;
    if (e     < end) { sA = csr_u[(eb+e  )*2]; wA = (H==4)? bf2f(ee16[(eb+e  )*4+h]) : bf2f(ee16[eb+e  ]); }
    if (e + 2 < end) { sB = csr_u[(eb+e+2)*2]; wB = (H==4)? bf2f(ee16[(eb+e+2)*4+h]) : bf2f(ee16[eb+e+2]); }

    while (e < end) {
        uint4 v0 = *(const uint4*)(feat + (size_t)sA*256 + flane*8);
        bool h1 = (e + 2 < end);
        uint4 v1 = make_uint4(0,0,0,0);
        if (h1) v1 = *(const uint4*)(feat + (size_t)sB*256 + flane*8);
        float w0 = wA, w1 = h1 ? wB : 0.f;
        if (e + 4 < end) { sA = csr_u[(eb+e+4)*2]; wA = (H==4)? bf2f(ee16[(eb+e+4)*4+h]) : bf2f(ee16[eb+e+4]); }
        if (e + 6 < end) { sB = csr_u[(eb+e+6)*2]; wB = (H==4)? bf2f(ee16[(eb+e+6)*4+h]) : bf2f(ee16[eb+e+6]); }
        den += w0 + w1;
        a[0] += w0*bflo(v0.x) + w1*bflo(v1.x);
        a[1] += w0*bfhi(v0.x) + w1*bfhi(v1.x);
        a[2] += w0*bflo(v0.y) + w1*bflo(v1.y);
        a[3] += w0*bfhi(v0.y) + w1*bfhi(v1.y);
        a[4] += w0*bflo(v0.z) + w1*bflo(v1.z);
        a[5] += w0*bfhi(v0.z) + w1*bfhi(v1.z);
        a[6] += w0*bflo(v0.w) + w1*bflo(v1.w);
        a[7] += w0*bfhi(v0.w) + w1*bfhi(v1.w);
        e += 4;
    }

    // combine the two edge-slots (lane ^ 32 holds the other slot's partial)
    #pragma unroll
    for (int j = 0; j < 8; ++j) a[j] += __shfl_xor(a[j], 32);
    den += __shfl_xor(den, 32);

    if (eslot == 0) {
        float inv = 1.f / (den + 1e-9f);
        #pragma unroll
        for (int j = 0; j < 8; ++j) {
            a[j] *= inv;
            if (RELU) a[j] = fmaxf(a[j], 0.f);
        }
        uint4 pk;
        pk.x = pk2bf(a[0], a[1]);
        pk.y = pk2bf(a[2], a[3]);
        pk.z = pk2bf(a[4], a[5]);
        pk.w = pk2bf(a[6], a[7]);
        *(uint4*)&z[((size_t)n*MM + m)*256 + flane*8] = pk;
    }
}

// ---------------- semantic attention (MFMA): wsum[m] += sum_n tanh(z@W+b)·v ----------------
__global__ __launch_bounds__(256) void semw_mfma_kernel(const unsigned short* __restrict__ Z,
                                                        const unsigned short* __restrict__ Wt,
                                                        const float* __restrict__ bias, const float* __restrict__ v,
                                                        float* __restrict__ wsum) {
    int tid = threadIdx.x;
    int w = tid >> 6, lane = tid & 63;
    int r0 = blockIdx.x*64 + w*16;
    int lrow = lane & 15, lk = lane >> 4;

    int arow = r0 + lrow;
    if (arow >= NN*MM) arow = NN*MM - 1;   // clamp; masked in epilogue
    bf16x8 a[8];
    const unsigned short* ap = Z + (size_t)arow*256 + lk*8;
    #pragma unroll
    for (int k = 0; k < 8; ++k) a[k] = *(const bf16x8*)(ap + k*32);

    float p[4] = {0.f, 0.f, 0.f, 0.f};
    #pragma unroll
    for (int n = 0; n < 8; ++n) {
        int col = n*16 + lrow;
        const unsigned short* bp = Wt + (size_t)col*256 + lk*8;
        f32x4 acc = {0.f, 0.f, 0.f, 0.f};
        #pragma unroll
        for (int k = 0; k < 8; ++k) {
            bf16x8 bfr = *(const bf16x8*)(bp + k*32);
            acc = __builtin_amdgcn_mfma_f32_16x16x32_bf16(a[k], bfr, acc, 0, 0, 0);
        }
        float bb = bias[col], vv = v[col];
        #pragma unroll
        for (int r = 0; r < 4; ++r)
            p[r] += tanhf(acc[r] + bb) * vv;
    }

    #pragma unroll
    for (int r = 0; r < 4; ++r) {
        #pragma unroll
        for (int o = 1; o < 16; o <<= 1) p[r] += __shfl_xor(p[r], o);
    }

    __shared__ float loc[3];
    if (tid < 3) loc[tid] = 0.f;
    __syncthreads();
    if (lrow == 0) {
        #pragma unroll
        for (int r = 0; r < 4; ++r) {
            int row = r0 + lk*4 + r;
            if (row < NN*MM) atomicAdd(&loc[row % MM], p[r]);
        }
    }
    __syncthreads();
    if (tid < 3) atomicAdd(&wsum[tid], loc[tid]);
}

// layer-1 combine: z (bf16) -> h (bf16); beta computed inline from wsum
__global__ __launch_bounds__(128) void combine_bf16_kernel(const unsigned short* __restrict__ z, const float* __restrict__ wsum,
                                                           unsigned short* __restrict__ outb) {
    __shared__ float bs[3];
    int n = blockIdx.x, t = threadIdx.x;
    if (t == 0) {
        float w0 = wsum[0] / (float)NN, w1 = wsum[1] / (float)NN, w2 = wsum[2] / (float)NN;
        float mx = fmaxf(w0, fmaxf(w1, w2));
        float e0 = expf(w0 - mx), e1 = expf(w1 - mx), e2 = expf(w2 - mx);
        float s = e0 + e1 + e2;
        bs[0] = e0 / s; bs[1] = e1 / s; bs[2] = e2 / s;
    }
    __syncthreads();
    float b0 = bs[0], b1 = bs[1], b2 = bs[2];
    size_t base = (size_t)n*MM*256 + t*2;
    unsigned z0 = *(const unsigned*)&z[base];
    unsigned z1 = *(const unsigned*)&z[base + 256];
    unsigned z2 = *(const unsigned*)&z[base + 512];
    float ox = b0*bflo(z0) + b1*bflo(z1) + b2*bflo(z2);
    float oy = b0*bfhi(z0) + b1*bfhi(z1) + b2*bfhi(z2);
    *(unsigned*)&outb[(size_t)n*256 + t*2] = pk2bf(ox, oy);
}

// layer-2 combine: z (bf16) -> out (fp32); also writes att_mp
__global__ __launch_bounds__(128) void combine_kernel(const unsigned short* __restrict__ z, const float* __restrict__ wsum,
                                                      float* __restrict__ out, float* __restrict__ att_out) {
    __shared__ float bs[3];
    int n = blockIdx.x, t = threadIdx.x;
    if (t == 0) {
        float w0 = wsum[0] / (float)NN, w1 = wsum[1] / (float)NN, w2 = wsum[2] / (float)NN;
        float mx = fmaxf(w0, fmaxf(w1, w2));
        float e0 = expf(w0 - mx), e1 = expf(w1 - mx), e2 = expf(w2 - mx);
        float s = e0 + e1 + e2;
        bs[0] = e0 / s; bs[1] = e1 / s; bs[2] = e2 / s;
        if (n == 0) { att_out[0] = bs[0]; att_out[1] = bs[1]; att_out[2] = bs[2]; }
    }
    __syncthreads();
    float b0 = bs[0], b1 = bs[1], b2 = bs[2];
    size_t base = (size_t)n*MM*256 + t*2;
    unsigned z0 = *(const unsigned*)&z[base];
    unsigned z1 = *(const unsigned*)&z[base + 256];
    unsigned z2 = *(const unsigned*)&z[base + 512];
    float2 o;
    o.x = b0*bflo(z0) + b1*bflo(z1) + b2*bflo(z2);
    o.y = b0*bfhi(z0) + b1*bfhi(z1) + b2*bfhi(z2);
    *(float2*)&out[(size_t)n*256 + t*2] = o;
}

extern "C" void kernel_launch(void* const* d_in, const int* in_sizes, int n_in,
                              void* d_out, int out_size, void* d_ws, size_t ws_size,
                              hipStream_t stream) {
    const float* x    = (const float*)d_in[0];
    const int*   edges= (const int*)  d_in[1];
    const float* W1   = (const float*)d_in[2];
    const float* al1  = (const float*)d_in[3];
    const float* ar1  = (const float*)d_in[4];
    const float* saW1 = (const float*)d_in[5];
    const float* sab1 = (const float*)d_in[6];
    const float* sav1 = (const float*)d_in[7];
    const float* W2   = (const float*)d_in[8];
    const float* al2  = (const float*)d_in[9];
    const float* ar2  = (const float*)d_in[10];
    const float* saW2 = (const float*)d_in[11];
    const float* sab2 = (const float*)d_in[12];
    const float* sav2 = (const float*)d_in[13];
    float* out = (float*)d_out;

    char* ws = (char*)d_ws;
    size_t off = 0;
    auto alloc = [&](size_t bytes) { void* p = ws + off; off += (bytes + 255) & ~(size_t)255; return p; };
    unsigned short* feat  = (unsigned short*)alloc((size_t)NN*256*2);      // bf16
    unsigned short* z     = (unsigned short*)alloc((size_t)NN*MM*256*2);   // bf16
    unsigned short* xb    = (unsigned short*)alloc((size_t)NN*256*2);      // bf16 x  (reused as hb)
    unsigned short* W1t   = (unsigned short*)alloc(256*256*2);
    unsigned short* saW1t = (unsigned short*)alloc(SAH*256*2);
    unsigned short* W2t   = (unsigned short*)alloc(256*256*2);
    unsigned short* saW2t = (unsigned short*)alloc(SAH*256*2);
    unsigned short* ee16  = (unsigned short*)alloc((size_t)MM*EE*4*2);     // bf16 coefficients
    float* el     = (float*)alloc(NN*4*4);
    float* er     = (float*)alloc(NN*4*4);
    float* wsum   = (float*)alloc(256);        // [0..3]=layer1, [4..7]=layer2
    int*   cnt    = (int*)alloc(MM*NN*4);
    int*   cursor = (int*)alloc(MM*NN*4);
    int*   rowptr = (int*)alloc(MM*(NN+1)*4);
    uint2* csr    = (uint2*)alloc((size_t)MM*EE*8);
    int*   bsum   = (int*)alloc(MM*NB*4);
    int*   boff   = (int*)alloc(MM*NB*4);
    unsigned short* hb = xb;   // layer-1 output (bf16), reuses xb space

    int egrid2 = (MM*EE/2 + 255)/256;
    int egrid4 = (MM*EE/4 + 255)/256;
    int chunks = (EE/4 + 255)/256;            // 313
    dim3 sg(NB, MM);

    // prep: x->bf16, weights -> transposed bf16, zero cnt/wsum
    prep_kernel<<<XBLK + 768 + ZBLK, 256, 0, stream>>>(x, xb, W1, W1t, saW1, saW1t, W2, W2t, saW2, saW2t, cnt, wsum);

    // CSR build (shared by both layers)
    hist_kernel<<<egrid4, 256, 0, stream>>>(edges, cnt);
    scanA_kernel<<<sg, 256, 0, stream>>>(cnt, rowptr, bsum);
    scanB_kernel<<<1, 128, 0, stream>>>(bsum, boff);
    scanC_kernel<<<sg, 256, 0, stream>>>(cnt, rowptr, boff, cursor);
    scatter_kernel<<<dim3(chunks*8, MM), 256, 0, stream>>>(edges, cursor, csr);

    // ---- layer 1 ----
    gemm_mfma_kernel<4><<<NN/32, 256, 0, stream>>>(xb, W1t, al1, ar1, feat, el, er);
    edge_ee_kernel<4><<<egrid2, 256, 0, stream>>>((const unsigned long long*)csr, el, er, ee16);
    agg_kernel<4, true><<<dim3(NN/4, MM), 256, 0, stream>>>(feat, ee16, rowptr, (const unsigned*)csr, z);
    semw_mfma_kernel<<<(NN*MM + 63)/64, 256, 0, stream>>>(z, saW1t, sab1, sav1, wsum);
    combine_bf16_kernel<<<NN, 128, 0, stream>>>(z, wsum, hb);

    // ---- layer 2 ----
    gemm_mfma_kernel<1><<<NN/32, 256, 0, stream>>>(hb, W2t, al2, ar2, feat, el, er);
    edge_ee_kernel<1><<<egrid2, 256, 0, stream>>>((const unsigned long long*)csr, el, er, ee16);
    agg_kernel<1, false><<<dim3(NN/4, MM), 256, 0, stream>>>(feat, ee16, rowptr, (const unsigned*)csr, z);
    semw_mfma_kernel<<<(NN*MM + 63)/64, 256, 0, stream>>>(z, saW2t, sab2, sav2, wsum + 4);
    combine_kernel<<<NN, 128, 0, stream>>>(z, wsum + 4, out, out + (size_t)NN*256);
}